// Round 15
// baseline (240.204 us; speedup 1.0000x reference)
//
#include <hip/hip_runtime.h>
#include <hip/hip_bf16.h>
#include <math.h>

// Problem constants
#define B_SZ 4
#define L_SZ 8192
#define DM 512           // D_MODEL
#define DMEM 512         // D_MEM
#define M1 (B_SZ * (L_SZ - 1))   // 32764 rows for the av GEMM
#define M2 (B_SZ * L_SZ)         // 32768 rows for GEMM2/3

typedef _Float16 h16;
typedef __attribute__((ext_vector_type(2))) _Float16 f16x2;
typedef __attribute__((ext_vector_type(8))) _Float16 f16x8;
typedef __attribute__((ext_vector_type(4))) float f32x4;

#define MFMA16(a, b, c) __builtin_amdgcn_mfma_f32_16x16x32_f16((a), (b), (c), 0, 0, 0)
#define WAVES_EU(mn, mx) __attribute__((amdgpu_waves_per_eu(mn, mx)))

// async global->LDS, 16B per lane
__device__ __forceinline__ void gl16(const void* g, void* l) {
    __builtin_amdgcn_global_load_lds(
        (const __attribute__((address_space(1))) void*)g,
        (__attribute__((address_space(3))) void*)l, 16, 0, 0);
}

// Swizzled LDS fragment read from a [128 rows][64 cols] fp16 tile (128 B rows).
__device__ __forceinline__ f16x8 lds_frag(const h16* base, int row, int col, int key) {
    return *(const f16x8*)((const char*)base + row * 128 + ((col * 2) ^ (key << 4)));
}

// XCD swizzle, A-reuse-friendly decode (by fast -> weight panel L2-resident).
__device__ __forceinline__ void xcd_remap(int& bx, int& by) {
    int gx = gridDim.x, gy = gridDim.y;
    int nwg = gx * gy;
    int lin = blockIdx.y * gx + blockIdx.x;
    int chunk = nwg >> 3;
    int l = (lin & 7) * chunk + (lin >> 3);
    by = l % gy;
    bx = l / gy;
}

// ---------------------------------------------------------------------------
// Merged precompute: x conv + all weight packs in ONE launch.
// ---------------------------------------------------------------------------
__global__ __launch_bounds__(256) void prep_all(
    const float* __restrict__ x, const float* __restrict__ Wgo,
    const float* __restrict__ Wav, const float* __restrict__ Wout,
    h16* __restrict__ xh, h16* __restrict__ Wgoh,
    h16* __restrict__ Wavh, h16* __restrict__ Wouth)
{
    int i = blockIdx.x * 256 + threadIdx.x;
    const float* s;
    h16* d;
    if (i < 2097152) {               // x
        int m = i >> 6, bb = i & 63;
        s = x + (size_t)m * 512 + bb * 8;
        d = xh + (size_t)m * 512 + (bb ^ (m & 7)) * 8;
    } else {
        int j = i - 2097152;
        if (j < 65536) {             // Wgo
            int r = j >> 7, bb = j & 127;
            s = Wgo + (size_t)r * 1024 + bb * 8;
            d = Wgoh + (size_t)r * 1024 + (bb ^ (r & 7)) * 8;
        } else if (j < 196608) {     // Wav
            int k = j - 65536;
            int P = k >> 6, bb = k & 63;
            int by = P >> 7, lo = P & 127;
            int half = lo >> 6, g = (lo >> 4) & 3, nl = lo & 15;
            int orig = g * 512 + by * 32 + half * 16 + nl;
            s = Wav + (size_t)orig * 512 + bb * 8;
            d = Wavh + (size_t)P * 512 + (bb ^ (P & 7)) * 8;
        } else {                     // Wout
            int k = j - 196608;
            int P = k >> 6, bb = k & 63;
            int by = P >> 7, lo = P & 127;
            int chunk = lo >> 5, g = (lo >> 4) & 1, nl = lo & 15;
            int orig = g * 512 + by * 64 + chunk * 16 + nl;
            s = Wout + (size_t)orig * 512 + bb * 8;
            d = Wouth + (size_t)P * 512 + (bb ^ (P & 7)) * 8;
        }
    }
    const float4* sv = (const float4*)s;
    float4 v0 = sv[0], v1 = sv[1];
    float vv[8] = {v0.x, v0.y, v0.z, v0.w, v1.x, v1.y, v1.z, v1.w};
    f16x8 hh;
    #pragma unroll
    for (int j = 0; j < 8; ++j) hh[j] = (h16)vv[j];
    *(f16x8*)d = hh;
}

// ---------------------------------------------------------------------------
// GEMM1: [M1 x 512] x [512 x 2048(packed 4 groups)] + NRU combine -> ms_inp
// (fp16). Single-buffer 32KB, WAVES_EU(4,4): 4 blocks/CU. (r14-proven: 75.5us,
// 910 TF effective = the 128^2 2-barrier structure ceiling.)
// ---------------------------------------------------------------------------
__global__ __launch_bounds__(256) WAVES_EU(4, 4) void gemm_av_mfma(
    const h16* __restrict__ xh, const h16* __restrict__ Wh,
    const float* __restrict__ bav, h16* __restrict__ ms_inp)
{
    __shared__ __align__(16) h16 As[128 * 64];   // 16 KB each
    __shared__ __align__(16) h16 Bh[128 * 64];

    int bx, by; xcd_remap(bx, by);
    const int tid = threadIdx.x, lane = tid & 63, w = tid >> 6;
    const int wm = (w & 1) * 64, wn = (w >> 1) * 64;
    const int bm = bx * 128;
    const int ln = lane & 15, ko = (lane >> 4) * 8;
    const int kb = ln & 7;
    char* lA = (char*)As; char* lH = (char*)Bh;
    const int wb = w * 1024;

    const char *aP[4], *hP[4];
    {
        const int r8 = lane >> 3, c16 = (lane & 7) * 16;
        #pragma unroll
        for (int i = 0; i < 4; ++i) {
            int row = i * 32 + w * 8 + r8;
            int mg = bm + row; if (mg > M1 - 1) mg = M1 - 1;
            size_t xr = (size_t)mg + (unsigned)mg / (L_SZ - 1);
            aP[i] = (const char*)xh + xr * (DM * 2) + c16;
            size_t br = (size_t)(by * 128 + row) * (DM * 2) + c16;
            hP[i] = (const char*)Wh + br;
        }
    }
    int ka[4];
    #pragma unroll
    for (int fm = 0; fm < 4; ++fm) {
        int m = bm + wm + fm * 16 + ln;
        int mg = m > M1 - 1 ? M1 - 1 : m;
        ka[fm] = (int)((mg + (unsigned)mg / (L_SZ - 1)) & 7);
    }

    f32x4 acc[4][4];
    #pragma unroll
    for (int i = 0; i < 4; ++i)
        #pragma unroll
        for (int j = 0; j < 4; ++j) acc[i][j] = (f32x4){0.f, 0.f, 0.f, 0.f};

#define STAGE_AV(koff) do { \
    gl16(aP[0] + (koff), lA + 0 * 4096 + wb); gl16(hP[0] + (koff), lH + 0 * 4096 + wb); \
    gl16(aP[1] + (koff), lA + 1 * 4096 + wb); gl16(hP[1] + (koff), lH + 1 * 4096 + wb); \
    gl16(aP[2] + (koff), lA + 2 * 4096 + wb); gl16(hP[2] + (koff), lH + 2 * 4096 + wb); \
    gl16(aP[3] + (koff), lA + 3 * 4096 + wb); gl16(hP[3] + (koff), lH + 3 * 4096 + wb); \
} while (0)

    STAGE_AV(0);
    for (int kt = 0; kt < 8; ++kt) {
        asm volatile("s_waitcnt vmcnt(0)" ::: "memory");
        __syncthreads();
        #pragma unroll
        for (int s = 0; s < 2; ++s) {
            const int c = s * 32 + ko;
            f16x8 a[4];
            #pragma unroll
            for (int fm = 0; fm < 4; ++fm)
                a[fm] = lds_frag(As, wm + fm * 16 + ln, c, ka[fm]);
            #pragma unroll
            for (int fn = 0; fn < 4; ++fn) {
                f16x8 vh = lds_frag(Bh, wn + fn * 16 + ln, c, kb);
                #pragma unroll
                for (int fm = 0; fm < 4; ++fm)
                    acc[fm][fn] = MFMA16(a[fm], vh, acc[fm][fn]);
            }
        }
        __syncthreads();
        if (kt < 7) STAGE_AV((kt + 1) * 128);
    }
#undef STAGE_AV

    // epilogue: fn = group; combine in-register; write fp16
    const int lm = (lane >> 4) * 4;
    const int nn = by * 32 + (wn >> 6) * 16 + ln;
    const float b0 = bav[nn], b1 = bav[nn + 512], b2 = bav[nn + 1024], b3 = bav[nn + 1536];
    #pragma unroll
    for (int fm = 0; fm < 4; ++fm) {
        #pragma unroll
        for (int i = 0; i < 4; ++i) {
            int m = bm + wm + fm * 16 + lm + i;
            if (m < M1) {
                float a0 = acc[fm][0][i] + b0;
                float a1 = acc[fm][1][i] + b1;
                float a2 = acc[fm][2][i] + b2;
                float a3 = acc[fm][3][i] + b3;
                ms_inp[(size_t)m * DMEM + nn] = (h16)(a0 * a1 - a2 * a3);
            }
        }
    }
}

// ---------------------------------------------------------------------------
// Chunked cumsum over fp16 ms_inp (fp32 accumulation). Chunk = 32 rows.
// ---------------------------------------------------------------------------
__global__ __launch_bounds__(256) void scan_pass1(
    const h16* __restrict__ ms_inp, float* __restrict__ csum)
{
    int b = blockIdx.y;
    int c = blockIdx.x * 4 + (threadIdx.x >> 6);    // 0..255
    int t = threadIdx.x & 63;
    int l0 = c * 32;
    int len = min(32, (L_SZ - 1) - l0);
    const h16* p = ms_inp + ((size_t)b * (L_SZ - 1) + l0) * DMEM + t * 8;
    float s[8] = {0.f, 0.f, 0.f, 0.f, 0.f, 0.f, 0.f, 0.f};
    for (int i = 0; i < len; ++i) {
        f16x8 v = *(const f16x8*)(p + (size_t)i * DMEM);
        #pragma unroll
        for (int j = 0; j < 8; ++j) s[j] += (float)v[j];
    }
    float* q = csum + ((size_t)b * 256 + c) * DMEM + t * 8;
    *(float4*)q       = make_float4(s[0], s[1], s[2], s[3]);
    *(float4*)(q + 4) = make_float4(s[4], s[5], s[6], s[7]);
}

__global__ __launch_bounds__(256) void scan_pass2(float* __restrict__ csum)
{
    __shared__ float wsum[4];
    int b = blockIdx.x >> 9, d = blockIdx.x & 511;
    int t = threadIdx.x, lane = t & 63, wv = t >> 6;
    float* p = csum + (size_t)b * 256 * DMEM + d;
    float v = p[(size_t)t * DMEM];
    #pragma unroll
    for (int off = 1; off < 64; off <<= 1) {
        float u = __shfl_up(v, off, 64);
        if (lane >= off) v += u;
    }
    if (lane == 63) wsum[wv] = v;
    __syncthreads();
    float add = 0.f;
    #pragma unroll
    for (int i = 0; i < 4; ++i) if (i < wv) add += wsum[i];
    v += add;
    float ex = __shfl_up(v, 1, 64);
    if (lane == 0) ex = add;
    p[(size_t)t * DMEM] = ex;
}

__global__ __launch_bounds__(256) void scan_pass3(
    const h16* __restrict__ ms_inp, const float* __restrict__ csum,
    h16* __restrict__ msh)
{
    int b = blockIdx.y;
    int c = blockIdx.x * 4 + (threadIdx.x >> 6);
    int t = threadIdx.x & 63;
    int l0 = c * 32;
    int len = min(32, (L_SZ - 1) - l0);
    const float* q = csum + ((size_t)b * 256 + c) * DMEM + t * 8;
    float run[8];
    #pragma unroll
    for (int j = 0; j < 8; ++j) run[j] = q[j];
    const h16* p = ms_inp + ((size_t)b * (L_SZ - 1) + l0) * DMEM + t * 8;
    if (c == 0) {
        f16x8 z = {};
        *(f16x8*)(msh + (size_t)b * L_SZ * DMEM + t * 8) = z;
    }
    for (int i = 0; i < len; ++i) {
        f16x8 v = *(const f16x8*)(p + (size_t)i * DMEM);
        f16x8 o;
        #pragma unroll
        for (int j = 0; j < 8; ++j) { run[j] += (float)v[j]; o[j] = (h16)run[j]; }
        int m = b * L_SZ + l0 + 1 + i;
        int db = t ^ (m & 7);
        *(f16x8*)(msh + (size_t)m * DMEM + db * 8) = o;
    }
}

// ---------------------------------------------------------------------------
// GEMM2: [M2 x 1024 (x||ms)] x [1024 x 512] + GELU -> yh (fp16, swizzled).
// Single-buffer 32KB, WAVES_EU(4,4) (av-proven config).
// ---------------------------------------------------------------------------
__global__ __launch_bounds__(256) WAVES_EU(4, 4) void gemm_go_mfma(
    const h16* __restrict__ xh, const h16* __restrict__ msh,
    const h16* __restrict__ Wh,
    const float* __restrict__ bgo, h16* __restrict__ yh)
{
    __shared__ __align__(16) h16 As[128 * 64];
    __shared__ __align__(16) h16 Bh[128 * 64];

    int bx, by; xcd_remap(bx, by);
    const int tid = threadIdx.x, lane = tid & 63, w = tid >> 6;
    const int wm = (w & 1) * 64, wn = (w >> 1) * 64;
    const int bm = bx * 128, bn = by * 128;
    const int ln = lane & 15, ko = (lane >> 4) * 8;
    const int kk = ln & 7;
    char* lA = (char*)As; char* lH = (char*)Bh;
    const int wb = w * 1024;

    const char *xP[4], *mP[4], *hP[4];
    {
        const int r8 = lane >> 3, c16 = (lane & 7) * 16;
        #pragma unroll
        for (int i = 0; i < 4; ++i) {
            int row = i * 32 + w * 8 + r8;
            size_t ar = (size_t)(bm + row) * (DM * 2) + c16;
            xP[i] = (const char*)xh + ar;
            mP[i] = (const char*)msh + ar;
            size_t br = (size_t)(bn + row) * (2 * DM * 2) + c16;
            hP[i] = (const char*)Wh + br;
        }
    }

    f32x4 acc[4][4];
    #pragma unroll
    for (int i = 0; i < 4; ++i)
        #pragma unroll
        for (int j = 0; j < 4; ++j) acc[i][j] = (f32x4){0.f, 0.f, 0.f, 0.f};

#define STAGE_GO(tt) do { \
    const int bo = (tt) * 128; \
    if ((tt) < 8) { \
        const int ao = (tt) * 128; \
        gl16(xP[0] + ao, lA + 0 * 4096 + wb); gl16(hP[0] + bo, lH + 0 * 4096 + wb); \
        gl16(xP[1] + ao, lA + 1 * 4096 + wb); gl16(hP[1] + bo, lH + 1 * 4096 + wb); \
        gl16(xP[2] + ao, lA + 2 * 4096 + wb); gl16(hP[2] + bo, lH + 2 * 4096 + wb); \
        gl16(xP[3] + ao, lA + 3 * 4096 + wb); gl16(hP[3] + bo, lH + 3 * 4096 + wb); \
    } else { \
        const int ao = ((tt) - 8) * 128; \
        gl16(mP[0] + ao, lA + 0 * 4096 + wb); gl16(hP[0] + bo, lH + 0 * 4096 + wb); \
        gl16(mP[1] + ao, lA + 1 * 4096 + wb); gl16(hP[1] + bo, lH + 1 * 4096 + wb); \
        gl16(mP[2] + ao, lA + 2 * 4096 + wb); gl16(hP[2] + bo, lH + 2 * 4096 + wb); \
        gl16(mP[3] + ao, lA + 3 * 4096 + wb); gl16(hP[3] + bo, lH + 3 * 4096 + wb); \
    } \
} while (0)

    STAGE_GO(0);
    for (int kt = 0; kt < 16; ++kt) {
        asm volatile("s_waitcnt vmcnt(0)" ::: "memory");
        __syncthreads();
        #pragma unroll
        for (int s = 0; s < 2; ++s) {
            const int c = s * 32 + ko;
            f16x8 a[4];
            #pragma unroll
            for (int fm = 0; fm < 4; ++fm)
                a[fm] = lds_frag(As, wm + fm * 16 + ln, c, kk);
            #pragma unroll
            for (int fn = 0; fn < 4; ++fn) {
                f16x8 vh = lds_frag(Bh, wn + fn * 16 + ln, c, kk);
                #pragma unroll
                for (int fm = 0; fm < 4; ++fm)
                    acc[fm][fn] = MFMA16(a[fm], vh, acc[fm][fn]);
            }
        }
        __syncthreads();
        if (kt < 15) STAGE_GO(kt + 1);
    }
#undef STAGE_GO

    const int lm = (lane >> 4) * 4;
    #pragma unroll
    for (int fm = 0; fm < 4; ++fm) {
        #pragma unroll
        for (int fn = 0; fn < 4; ++fn) {
            int n = bn + wn + fn * 16 + ln;
            float bias = bgo[n];
            #pragma unroll
            for (int i = 0; i < 4; ++i) {
                int m = bm + wm + fm * 16 + lm + i;
                float t = acc[fm][fn][i] + bias;
                float g = 0.5f * t * (1.0f + erff(t * 0.70710678118654752f));
                int nsw = (((n >> 3) ^ (m & 7)) << 3) | (n & 7);
                yh[(size_t)m * DM + nsw] = (h16)g;
            }
        }
    }
}

// ---------------------------------------------------------------------------
// GEMM3: [M2 x 512] x [512 x 1024(packed 2 groups)] + GLU -> out (fp32).
// Single-buffer 32KB, WAVES_EU(4,4) (av-proven config).
// ---------------------------------------------------------------------------
__global__ __launch_bounds__(256) WAVES_EU(4, 4) void gemm_out_mfma(
    const h16* __restrict__ yh, const h16* __restrict__ Wh,
    const float* __restrict__ bout, float* __restrict__ out)
{
    __shared__ __align__(16) h16 As[128 * 64];
    __shared__ __align__(16) h16 Bh[128 * 64];

    int bx, by; xcd_remap(bx, by);
    const int tid = threadIdx.x, lane = tid & 63, w = tid >> 6;
    const int wm = (w & 1) * 64, wn = (w >> 1) * 64;
    const int bm = bx * 128;
    const int ln = lane & 15, ko = (lane >> 4) * 8;
    const int kk = ln & 7;
    char* lA = (char*)As; char* lH = (char*)Bh;
    const int wb = w * 1024;

    const char *aP[4], *hP[4];
    {
        const int r8 = lane >> 3, c16 = (lane & 7) * 16;
        #pragma unroll
        for (int i = 0; i < 4; ++i) {
            int row = i * 32 + w * 8 + r8;
            aP[i] = (const char*)yh + (size_t)(bm + row) * (DM * 2) + c16;
            size_t br = (size_t)(by * 128 + row) * (DM * 2) + c16;
            hP[i] = (const char*)Wh + br;
        }
    }

    f32x4 acc[4][4];
    #pragma unroll
    for (int i = 0; i < 4; ++i)
        #pragma unroll
        for (int j = 0; j < 4; ++j) acc[i][j] = (f32x4){0.f, 0.f, 0.f, 0.f};

#define STAGE_OUT(koff) do { \
    gl16(aP[0] + (koff), lA + 0 * 4096 + wb); gl16(hP[0] + (koff), lH + 0 * 4096 + wb); \
    gl16(aP[1] + (koff), lA + 1 * 4096 + wb); gl16(hP[1] + (koff), lH + 1 * 4096 + wb); \
    gl16(aP[2] + (koff), lA + 2 * 4096 + wb); gl16(hP[2] + (koff), lH + 2 * 4096 + wb); \
    gl16(aP[3] + (koff), lA + 3 * 4096 + wb); gl16(hP[3] + (koff), lH + 3 * 4096 + wb); \
} while (0)

    STAGE_OUT(0);
    for (int kt = 0; kt < 8; ++kt) {
        asm volatile("s_waitcnt vmcnt(0)" ::: "memory");
        __syncthreads();
        #pragma unroll
        for (int s = 0; s < 2; ++s) {
            const int c = s * 32 + ko;
            f16x8 a[4];
            #pragma unroll
            for (int fm = 0; fm < 4; ++fm)
                a[fm] = lds_frag(As, wm + fm * 16 + ln, c, kk);
            #pragma unroll
            for (int fn = 0; fn < 4; ++fn) {
                f16x8 vh = lds_frag(Bh, wn + fn * 16 + ln, c, kk);
                #pragma unroll
                for (int fm = 0; fm < 4; ++fm)
                    acc[fm][fn] = MFMA16(a[fm], vh, acc[fm][fn]);
            }
        }
        __syncthreads();
        if (kt < 7) STAGE_OUT((kt + 1) * 128);
    }
#undef STAGE_OUT

    const int lm = (lane >> 4) * 4;
    #pragma unroll
    for (int fm = 0; fm < 4; ++fm) {
        #pragma unroll
        for (int cp = 0; cp < 2; ++cp) {
            int ncol = by * 64 + ((wn >> 5) + cp) * 16 + ln;
            float bz0 = bout[ncol], bz1 = bout[ncol + 512];
            #pragma unroll
            for (int i = 0; i < 4; ++i) {
                int m = bm + wm + fm * 16 + lm + i;
                float z0 = acc[fm][cp * 2 + 0][i] + bz0;
                float z1 = acc[fm][cp * 2 + 1][i] + bz1;
                out[(size_t)m * DM + ncol] = z0 * (1.0f / (1.0f + expf(-z1)));
            }
        }
    }
}

// ---------------------------------------------------------------------------
extern "C" void kernel_launch(void* const* d_in, const int* in_sizes, int n_in,
                              void* d_out, int out_size, void* d_ws, size_t ws_size,
                              hipStream_t stream)
{
    const float* x    = (const float*)d_in[0];
    const float* Wav  = (const float*)d_in[1];
    const float* bav  = (const float*)d_in[2];
    const float* Wgo  = (const float*)d_in[3];
    const float* bgo  = (const float*)d_in[4];
    const float* Wout = (const float*)d_in[5];
    const float* bout = (const float*)d_in[6];
    float* out = (float*)d_out;

    char* ws = (char*)d_ws;
    const size_t MB = 1 << 20;
    h16*   ms_inp = (h16*)ws;                     // 32 MiB [32764,512] fp16
    h16*   yh     = (h16*)(ws + 32 * MB);         // 32 MiB (after scan)
    h16*   xh     = (h16*)(ws + 64 * MB);         // 32 MiB (swizzled fp16)
    h16*   msh    = (h16*)(ws + 96 * MB);         // 32 MiB (swizzled fp16)
    h16*   Wavh   = (h16*)(ws + 129 * MB);        // 2 MiB (packed+swizzled)
    h16*   Wgoh   = (h16*)(ws + 131 * MB);        // 1 MiB
    h16*   Wouth  = (h16*)(ws + 132 * MB);        // 1 MiB
    float* csum   = (float*)(ws + 133 * MB);      // 2 MiB [B][256][512] f32

    // 0) precompute fp16 forms (one launch)
    prep_all<<<9216, 256, 0, stream>>>(x, Wgo, Wav, Wout, xh, Wgoh, Wavh, Wouth);
    // 1) av GEMM + NRU combine -> ms_inp (fp16)
    gemm_av_mfma<<<dim3(256, 16), 256, 0, stream>>>(xh, Wavh, bav, ms_inp);
    // 2-4) chunked cumsum -> msh (fp16, swizzled)
    scan_pass1<<<dim3(64, B_SZ), 256, 0, stream>>>(ms_inp, csum);
    scan_pass2<<<2048, 256, 0, stream>>>(csum);
    scan_pass3<<<dim3(64, B_SZ), 256, 0, stream>>>(ms_inp, csum, msh);
    // 5) SSM-in GEMM + GELU -> yh (fp16 swizzled)
    gemm_go_mfma<<<dim3(256, 4), 256, 0, stream>>>(xh, msh, Wgoh, bgo, yh);
    // 6) output GEMM + GLU -> out (f32)
    gemm_out_mfma<<<dim3(256, 8), 256, 0, stream>>>(yh, Wouth, bout, out);
}

// Round 16
// 237.098 us; speedup vs baseline: 1.0131x; 1.0131x over previous
//
#include <hip/hip_runtime.h>
#include <hip/hip_bf16.h>
#include <math.h>

// Problem constants
#define B_SZ 4
#define L_SZ 8192
#define DM 512           // D_MODEL
#define DMEM 512         // D_MEM
#define M1 (B_SZ * (L_SZ - 1))   // 32764 rows for the av GEMM
#define M2 (B_SZ * L_SZ)         // 32768 rows for GEMM2/3

typedef _Float16 h16;
typedef __attribute__((ext_vector_type(2))) _Float16 f16x2;
typedef __attribute__((ext_vector_type(8))) _Float16 f16x8;
typedef __attribute__((ext_vector_type(4))) float f32x4;

#define MFMA16(a, b, c) __builtin_amdgcn_mfma_f32_16x16x32_f16((a), (b), (c), 0, 0, 0)
#define WAVES_EU(mn, mx) __attribute__((amdgpu_waves_per_eu(mn, mx)))

// async global->LDS, 16B per lane
__device__ __forceinline__ void gl16(const void* g, void* l) {
    __builtin_amdgcn_global_load_lds(
        (const __attribute__((address_space(1))) void*)g,
        (__attribute__((address_space(3))) void*)l, 16, 0, 0);
}

// Swizzled LDS fragment read from a [128 rows][64 cols] fp16 tile (128 B rows).
__device__ __forceinline__ f16x8 lds_frag(const h16* base, int row, int col, int key) {
    return *(const f16x8*)((const char*)base + row * 128 + ((col * 2) ^ (key << 4)));
}

// XCD swizzle, A-reuse-friendly decode (by fast -> weight panel L2-resident).
__device__ __forceinline__ void xcd_remap(int& bx, int& by) {
    int gx = gridDim.x, gy = gridDim.y;
    int nwg = gx * gy;
    int lin = blockIdx.y * gx + blockIdx.x;
    int chunk = nwg >> 3;
    int l = (lin & 7) * chunk + (lin >> 3);
    by = l % gy;
    bx = l / gy;
}

// ---------------------------------------------------------------------------
// Merged precompute: x conv + all weight packs in ONE launch.
// ---------------------------------------------------------------------------
__global__ __launch_bounds__(256) void prep_all(
    const float* __restrict__ x, const float* __restrict__ Wgo,
    const float* __restrict__ Wav, const float* __restrict__ Wout,
    h16* __restrict__ xh, h16* __restrict__ Wgoh,
    h16* __restrict__ Wavh, h16* __restrict__ Wouth)
{
    int i = blockIdx.x * 256 + threadIdx.x;
    const float* s;
    h16* d;
    if (i < 2097152) {               // x
        int m = i >> 6, bb = i & 63;
        s = x + (size_t)m * 512 + bb * 8;
        d = xh + (size_t)m * 512 + (bb ^ (m & 7)) * 8;
    } else {
        int j = i - 2097152;
        if (j < 65536) {             // Wgo
            int r = j >> 7, bb = j & 127;
            s = Wgo + (size_t)r * 1024 + bb * 8;
            d = Wgoh + (size_t)r * 1024 + (bb ^ (r & 7)) * 8;
        } else if (j < 196608) {     // Wav
            int k = j - 65536;
            int P = k >> 6, bb = k & 63;
            int by = P >> 7, lo = P & 127;
            int half = lo >> 6, g = (lo >> 4) & 3, nl = lo & 15;
            int orig = g * 512 + by * 32 + half * 16 + nl;
            s = Wav + (size_t)orig * 512 + bb * 8;
            d = Wavh + (size_t)P * 512 + (bb ^ (P & 7)) * 8;
        } else {                     // Wout
            int k = j - 196608;
            int P = k >> 6, bb = k & 63;
            int by = P >> 7, lo = P & 127;
            int chunk = lo >> 5, g = (lo >> 4) & 1, nl = lo & 15;
            int orig = g * 512 + by * 64 + chunk * 16 + nl;
            s = Wout + (size_t)orig * 512 + bb * 8;
            d = Wouth + (size_t)P * 512 + (bb ^ (P & 7)) * 8;
        }
    }
    const float4* sv = (const float4*)s;
    float4 v0 = sv[0], v1 = sv[1];
    float vv[8] = {v0.x, v0.y, v0.z, v0.w, v1.x, v1.y, v1.z, v1.w};
    f16x8 hh;
    #pragma unroll
    for (int j = 0; j < 8; ++j) hh[j] = (h16)vv[j];
    *(f16x8*)d = hh;
}

// Pipeline sync helpers for the dbuf kernels (raw barrier keeps prefetch alive)
#define PIPE_WAIT(N) do { \
    asm volatile("s_waitcnt vmcnt(" #N ")" ::: "memory"); \
    __builtin_amdgcn_s_barrier(); \
    asm volatile("" ::: "memory"); \
} while (0)
#define PIPE_POST() do { \
    __builtin_amdgcn_s_barrier(); \
    asm volatile("" ::: "memory"); \
} while (0)

// ---------------------------------------------------------------------------
// GEMM1: [M1 x 512] x [512 x 2048(packed 4 groups)] + NRU combine -> ms_inp
// (fp16). Single-buffer 32KB, WAVES_EU(4,4): 4 blocks/CU — deep grid (4096
// blocks) gives cross-block TLP that hides the per-tile drain (r14: 75.5us).
// ---------------------------------------------------------------------------
__global__ __launch_bounds__(256) WAVES_EU(4, 4) void gemm_av_mfma(
    const h16* __restrict__ xh, const h16* __restrict__ Wh,
    const float* __restrict__ bav, h16* __restrict__ ms_inp)
{
    __shared__ __align__(16) h16 As[128 * 64];   // 16 KB each
    __shared__ __align__(16) h16 Bh[128 * 64];

    int bx, by; xcd_remap(bx, by);
    const int tid = threadIdx.x, lane = tid & 63, w = tid >> 6;
    const int wm = (w & 1) * 64, wn = (w >> 1) * 64;
    const int bm = bx * 128;
    const int ln = lane & 15, ko = (lane >> 4) * 8;
    const int kb = ln & 7;
    char* lA = (char*)As; char* lH = (char*)Bh;
    const int wb = w * 1024;

    const char *aP[4], *hP[4];
    {
        const int r8 = lane >> 3, c16 = (lane & 7) * 16;
        #pragma unroll
        for (int i = 0; i < 4; ++i) {
            int row = i * 32 + w * 8 + r8;
            int mg = bm + row; if (mg > M1 - 1) mg = M1 - 1;
            size_t xr = (size_t)mg + (unsigned)mg / (L_SZ - 1);
            aP[i] = (const char*)xh + xr * (DM * 2) + c16;
            size_t br = (size_t)(by * 128 + row) * (DM * 2) + c16;
            hP[i] = (const char*)Wh + br;
        }
    }
    int ka[4];
    #pragma unroll
    for (int fm = 0; fm < 4; ++fm) {
        int m = bm + wm + fm * 16 + ln;
        int mg = m > M1 - 1 ? M1 - 1 : m;
        ka[fm] = (int)((mg + (unsigned)mg / (L_SZ - 1)) & 7);
    }

    f32x4 acc[4][4];
    #pragma unroll
    for (int i = 0; i < 4; ++i)
        #pragma unroll
        for (int j = 0; j < 4; ++j) acc[i][j] = (f32x4){0.f, 0.f, 0.f, 0.f};

#define STAGE_AV(koff) do { \
    gl16(aP[0] + (koff), lA + 0 * 4096 + wb); gl16(hP[0] + (koff), lH + 0 * 4096 + wb); \
    gl16(aP[1] + (koff), lA + 1 * 4096 + wb); gl16(hP[1] + (koff), lH + 1 * 4096 + wb); \
    gl16(aP[2] + (koff), lA + 2 * 4096 + wb); gl16(hP[2] + (koff), lH + 2 * 4096 + wb); \
    gl16(aP[3] + (koff), lA + 3 * 4096 + wb); gl16(hP[3] + (koff), lH + 3 * 4096 + wb); \
} while (0)

    STAGE_AV(0);
    for (int kt = 0; kt < 8; ++kt) {
        asm volatile("s_waitcnt vmcnt(0)" ::: "memory");
        __syncthreads();
        #pragma unroll
        for (int s = 0; s < 2; ++s) {
            const int c = s * 32 + ko;
            f16x8 a[4];
            #pragma unroll
            for (int fm = 0; fm < 4; ++fm)
                a[fm] = lds_frag(As, wm + fm * 16 + ln, c, ka[fm]);
            #pragma unroll
            for (int fn = 0; fn < 4; ++fn) {
                f16x8 vh = lds_frag(Bh, wn + fn * 16 + ln, c, kb);
                #pragma unroll
                for (int fm = 0; fm < 4; ++fm)
                    acc[fm][fn] = MFMA16(a[fm], vh, acc[fm][fn]);
            }
        }
        __syncthreads();
        if (kt < 7) STAGE_AV((kt + 1) * 128);
    }
#undef STAGE_AV

    // epilogue: fn = group; combine in-register; write fp16
    const int lm = (lane >> 4) * 4;
    const int nn = by * 32 + (wn >> 6) * 16 + ln;
    const float b0 = bav[nn], b1 = bav[nn + 512], b2 = bav[nn + 1024], b3 = bav[nn + 1536];
    #pragma unroll
    for (int fm = 0; fm < 4; ++fm) {
        #pragma unroll
        for (int i = 0; i < 4; ++i) {
            int m = bm + wm + fm * 16 + lm + i;
            if (m < M1) {
                float a0 = acc[fm][0][i] + b0;
                float a1 = acc[fm][1][i] + b1;
                float a2 = acc[fm][2][i] + b2;
                float a3 = acc[fm][3][i] + b3;
                ms_inp[(size_t)m * DMEM + nn] = (h16)(a0 * a1 - a2 * a3);
            }
        }
    }
}

// ---------------------------------------------------------------------------
// Chunked cumsum over fp16 ms_inp (fp32 accumulation). Chunk = 32 rows.
// ---------------------------------------------------------------------------
__global__ __launch_bounds__(256) void scan_pass1(
    const h16* __restrict__ ms_inp, float* __restrict__ csum)
{
    int b = blockIdx.y;
    int c = blockIdx.x * 4 + (threadIdx.x >> 6);    // 0..255
    int t = threadIdx.x & 63;
    int l0 = c * 32;
    int len = min(32, (L_SZ - 1) - l0);
    const h16* p = ms_inp + ((size_t)b * (L_SZ - 1) + l0) * DMEM + t * 8;
    float s[8] = {0.f, 0.f, 0.f, 0.f, 0.f, 0.f, 0.f, 0.f};
    for (int i = 0; i < len; ++i) {
        f16x8 v = *(const f16x8*)(p + (size_t)i * DMEM);
        #pragma unroll
        for (int j = 0; j < 8; ++j) s[j] += (float)v[j];
    }
    float* q = csum + ((size_t)b * 256 + c) * DMEM + t * 8;
    *(float4*)q       = make_float4(s[0], s[1], s[2], s[3]);
    *(float4*)(q + 4) = make_float4(s[4], s[5], s[6], s[7]);
}

__global__ __launch_bounds__(256) void scan_pass2(float* __restrict__ csum)
{
    __shared__ float wsum[4];
    int b = blockIdx.x >> 9, d = blockIdx.x & 511;
    int t = threadIdx.x, lane = t & 63, wv = t >> 6;
    float* p = csum + (size_t)b * 256 * DMEM + d;
    float v = p[(size_t)t * DMEM];
    #pragma unroll
    for (int off = 1; off < 64; off <<= 1) {
        float u = __shfl_up(v, off, 64);
        if (lane >= off) v += u;
    }
    if (lane == 63) wsum[wv] = v;
    __syncthreads();
    float add = 0.f;
    #pragma unroll
    for (int i = 0; i < 4; ++i) if (i < wv) add += wsum[i];
    v += add;
    float ex = __shfl_up(v, 1, 64);
    if (lane == 0) ex = add;
    p[(size_t)t * DMEM] = ex;
}

__global__ __launch_bounds__(256) void scan_pass3(
    const h16* __restrict__ ms_inp, const float* __restrict__ csum,
    h16* __restrict__ msh)
{
    int b = blockIdx.y;
    int c = blockIdx.x * 4 + (threadIdx.x >> 6);
    int t = threadIdx.x & 63;
    int l0 = c * 32;
    int len = min(32, (L_SZ - 1) - l0);
    const float* q = csum + ((size_t)b * 256 + c) * DMEM + t * 8;
    float run[8];
    #pragma unroll
    for (int j = 0; j < 8; ++j) run[j] = q[j];
    const h16* p = ms_inp + ((size_t)b * (L_SZ - 1) + l0) * DMEM + t * 8;
    if (c == 0) {
        f16x8 z = {};
        *(f16x8*)(msh + (size_t)b * L_SZ * DMEM + t * 8) = z;
    }
    for (int i = 0; i < len; ++i) {
        f16x8 v = *(const f16x8*)(p + (size_t)i * DMEM);
        f16x8 o;
        #pragma unroll
        for (int j = 0; j < 8; ++j) { run[j] += (float)v[j]; o[j] = (h16)run[j]; }
        int m = b * L_SZ + l0 + 1 + i;
        int db = t ^ (m & 7);
        *(f16x8*)(msh + (size_t)m * DMEM + db * 8) = o;
    }
}

// ---------------------------------------------------------------------------
// GEMM2: [M2 x 1024 (x||ms)] x [1024 x 512] + GELU -> yh (fp16, swizzled).
// Double-buffered issue-early pipeline, WAVES_EU(2,2) — shallow grid (1024
// blocks): intra-block dbuf beats cross-block TLP here (r15 A/B).
// ---------------------------------------------------------------------------
__global__ __launch_bounds__(256) WAVES_EU(2, 2) void gemm_go_mfma(
    const h16* __restrict__ xh, const h16* __restrict__ msh,
    const h16* __restrict__ Wh,
    const float* __restrict__ bgo, h16* __restrict__ yh)
{
    __shared__ __align__(16) h16 As[2][128 * 64];
    __shared__ __align__(16) h16 Bh[2][128 * 64];

    int bx, by; xcd_remap(bx, by);
    const int tid = threadIdx.x, lane = tid & 63, w = tid >> 6;
    const int wm = (w & 1) * 64, wn = (w >> 1) * 64;
    const int bm = bx * 128, bn = by * 128;
    const int ln = lane & 15, ko = (lane >> 4) * 8;
    const int kk = ln & 7;
    const int wb = w * 1024;

    const char *xP[4], *mP[4], *hP[4];
    {
        const int r8 = lane >> 3, c16 = (lane & 7) * 16;
        #pragma unroll
        for (int i = 0; i < 4; ++i) {
            int row = i * 32 + w * 8 + r8;
            size_t ar = (size_t)(bm + row) * (DM * 2) + c16;
            xP[i] = (const char*)xh + ar;
            mP[i] = (const char*)msh + ar;
            size_t br = (size_t)(bn + row) * (2 * DM * 2) + c16;
            hP[i] = (const char*)Wh + br;
        }
    }

    f32x4 acc[4][4];
    #pragma unroll
    for (int i = 0; i < 4; ++i)
        #pragma unroll
        for (int j = 0; j < 4; ++j) acc[i][j] = (f32x4){0.f, 0.f, 0.f, 0.f};

#define STAGE_GO(tt, sel) do { \
    char* dA = (char*)As[sel]; char* dB = (char*)Bh[sel]; \
    const int bo = (tt) * 128; \
    if ((tt) < 8) { \
        const int ao = (tt) * 128; \
        gl16(xP[0] + ao, dA + 0 * 4096 + wb); gl16(hP[0] + bo, dB + 0 * 4096 + wb); \
        gl16(xP[1] + ao, dA + 1 * 4096 + wb); gl16(hP[1] + bo, dB + 1 * 4096 + wb); \
        gl16(xP[2] + ao, dA + 2 * 4096 + wb); gl16(hP[2] + bo, dB + 2 * 4096 + wb); \
        gl16(xP[3] + ao, dA + 3 * 4096 + wb); gl16(hP[3] + bo, dB + 3 * 4096 + wb); \
    } else { \
        const int ao = ((tt) - 8) * 128; \
        gl16(mP[0] + ao, dA + 0 * 4096 + wb); gl16(hP[0] + bo, dB + 0 * 4096 + wb); \
        gl16(mP[1] + ao, dA + 1 * 4096 + wb); gl16(hP[1] + bo, dB + 1 * 4096 + wb); \
        gl16(mP[2] + ao, dA + 2 * 4096 + wb); gl16(hP[2] + bo, dB + 2 * 4096 + wb); \
        gl16(mP[3] + ao, dA + 3 * 4096 + wb); gl16(hP[3] + bo, dB + 3 * 4096 + wb); \
    } \
} while (0)

    STAGE_GO(0, 0);
    STAGE_GO(1, 1);
    for (int kt = 0; kt < 16; ++kt) {
        if (kt < 15) PIPE_WAIT(8); else PIPE_WAIT(0);
        const h16* A = As[kt & 1];
        const h16* B = Bh[kt & 1];
        #pragma unroll
        for (int s = 0; s < 2; ++s) {
            const int c = s * 32 + ko;
            f16x8 a[4];
            #pragma unroll
            for (int fm = 0; fm < 4; ++fm)
                a[fm] = lds_frag(A, wm + fm * 16 + ln, c, kk);
            #pragma unroll
            for (int fn = 0; fn < 4; ++fn) {
                f16x8 vh = lds_frag(B, wn + fn * 16 + ln, c, kk);
                #pragma unroll
                for (int fm = 0; fm < 4; ++fm)
                    acc[fm][fn] = MFMA16(a[fm], vh, acc[fm][fn]);
            }
        }
        PIPE_POST();
        if (kt + 2 < 16) STAGE_GO(kt + 2, kt & 1);
    }
#undef STAGE_GO

    const int lm = (lane >> 4) * 4;
    #pragma unroll
    for (int fm = 0; fm < 4; ++fm) {
        #pragma unroll
        for (int fn = 0; fn < 4; ++fn) {
            int n = bn + wn + fn * 16 + ln;
            float bias = bgo[n];
            #pragma unroll
            for (int i = 0; i < 4; ++i) {
                int m = bm + wm + fm * 16 + lm + i;
                float t = acc[fm][fn][i] + bias;
                float g = 0.5f * t * (1.0f + erff(t * 0.70710678118654752f));
                int nsw = (((n >> 3) ^ (m & 7)) << 3) | (n & 7);
                yh[(size_t)m * DM + nsw] = (h16)g;
            }
        }
    }
}

// ---------------------------------------------------------------------------
// GEMM3: [M2 x 512] x [512 x 1024(packed 2 groups)] + GLU -> out (fp32).
// Double-buffered issue-early pipeline, WAVES_EU(2,2).
// ---------------------------------------------------------------------------
__global__ __launch_bounds__(256) WAVES_EU(2, 2) void gemm_out_mfma(
    const h16* __restrict__ yh, const h16* __restrict__ Wh,
    const float* __restrict__ bout, float* __restrict__ out)
{
    __shared__ __align__(16) h16 As[2][128 * 64];
    __shared__ __align__(16) h16 Bh[2][128 * 64];

    int bx, by; xcd_remap(bx, by);
    const int tid = threadIdx.x, lane = tid & 63, w = tid >> 6;
    const int wm = (w & 1) * 64, wn = (w >> 1) * 64;
    const int bm = bx * 128;
    const int ln = lane & 15, ko = (lane >> 4) * 8;
    const int kk = ln & 7;
    const int wb = w * 1024;

    const char *aP[4], *hP[4];
    {
        const int r8 = lane >> 3, c16 = (lane & 7) * 16;
        #pragma unroll
        for (int i = 0; i < 4; ++i) {
            int row = i * 32 + w * 8 + r8;
            aP[i] = (const char*)yh + (size_t)(bm + row) * (DM * 2) + c16;
            size_t br = (size_t)(by * 128 + row) * (DM * 2) + c16;
            hP[i] = (const char*)Wh + br;
        }
    }

    f32x4 acc[4][4];
    #pragma unroll
    for (int i = 0; i < 4; ++i)
        #pragma unroll
        for (int j = 0; j < 4; ++j) acc[i][j] = (f32x4){0.f, 0.f, 0.f, 0.f};

#define STAGE_OUT(koff, sel) do { \
    char* dA = (char*)As[sel]; char* dB = (char*)Bh[sel]; \
    gl16(aP[0] + (koff), dA + 0 * 4096 + wb); gl16(hP[0] + (koff), dB + 0 * 4096 + wb); \
    gl16(aP[1] + (koff), dA + 1 * 4096 + wb); gl16(hP[1] + (koff), dB + 1 * 4096 + wb); \
    gl16(aP[2] + (koff), dA + 2 * 4096 + wb); gl16(hP[2] + (koff), dB + 2 * 4096 + wb); \
    gl16(aP[3] + (koff), dA + 3 * 4096 + wb); gl16(hP[3] + (koff), dB + 3 * 4096 + wb); \
} while (0)

    STAGE_OUT(0, 0);
    STAGE_OUT(128, 1);
    for (int kt = 0; kt < 8; ++kt) {
        if (kt < 7) PIPE_WAIT(8); else PIPE_WAIT(0);
        const h16* A = As[kt & 1];
        const h16* B = Bh[kt & 1];
        #pragma unroll
        for (int s = 0; s < 2; ++s) {
            const int c = s * 32 + ko;
            f16x8 a[4];
            #pragma unroll
            for (int fm = 0; fm < 4; ++fm)
                a[fm] = lds_frag(A, wm + fm * 16 + ln, c, kk);
            #pragma unroll
            for (int fn = 0; fn < 4; ++fn) {
                f16x8 vh = lds_frag(B, wn + fn * 16 + ln, c, kk);
                #pragma unroll
                for (int fm = 0; fm < 4; ++fm)
                    acc[fm][fn] = MFMA16(a[fm], vh, acc[fm][fn]);
            }
        }
        PIPE_POST();
        if (kt + 2 < 8) STAGE_OUT((kt + 2) * 128, kt & 1);
    }
#undef STAGE_OUT

    const int lm = (lane >> 4) * 4;
    #pragma unroll
    for (int fm = 0; fm < 4; ++fm) {
        #pragma unroll
        for (int cp = 0; cp < 2; ++cp) {
            int ncol = by * 64 + ((wn >> 5) + cp) * 16 + ln;
            float bz0 = bout[ncol], bz1 = bout[ncol + 512];
            #pragma unroll
            for (int i = 0; i < 4; ++i) {
                int m = bm + wm + fm * 16 + lm + i;
                float z0 = acc[fm][cp * 2 + 0][i] + bz0;
                float z1 = acc[fm][cp * 2 + 1][i] + bz1;
                out[(size_t)m * DM + ncol] = z0 * (1.0f / (1.0f + expf(-z1)));
            }
        }
    }
}

// ---------------------------------------------------------------------------
extern "C" void kernel_launch(void* const* d_in, const int* in_sizes, int n_in,
                              void* d_out, int out_size, void* d_ws, size_t ws_size,
                              hipStream_t stream)
{
    const float* x    = (const float*)d_in[0];
    const float* Wav  = (const float*)d_in[1];
    const float* bav  = (const float*)d_in[2];
    const float* Wgo  = (const float*)d_in[3];
    const float* bgo  = (const float*)d_in[4];
    const float* Wout = (const float*)d_in[5];
    const float* bout = (const float*)d_in[6];
    float* out = (float*)d_out;

    char* ws = (char*)d_ws;
    const size_t MB = 1 << 20;
    h16*   ms_inp = (h16*)ws;                     // 32 MiB [32764,512] fp16
    h16*   yh     = (h16*)(ws + 32 * MB);         // 32 MiB (after scan)
    h16*   xh     = (h16*)(ws + 64 * MB);         // 32 MiB (swizzled fp16)
    h16*   msh    = (h16*)(ws + 96 * MB);         // 32 MiB (swizzled fp16)
    h16*   Wavh   = (h16*)(ws + 129 * MB);        // 2 MiB (packed+swizzled)
    h16*   Wgoh   = (h16*)(ws + 131 * MB);        // 1 MiB
    h16*   Wouth  = (h16*)(ws + 132 * MB);        // 1 MiB
    float* csum   = (float*)(ws + 133 * MB);      // 2 MiB [B][256][512] f32

    // 0) precompute fp16 forms (one launch)
    prep_all<<<9216, 256, 0, stream>>>(x, Wgo, Wav, Wout, xh, Wgoh, Wavh, Wouth);
    // 1) av GEMM + NRU combine -> ms_inp (fp16)
    gemm_av_mfma<<<dim3(256, 16), 256, 0, stream>>>(xh, Wavh, bav, ms_inp);
    // 2-4) chunked cumsum -> msh (fp16, swizzled)
    scan_pass1<<<dim3(64, B_SZ), 256, 0, stream>>>(ms_inp, csum);
    scan_pass2<<<2048, 256, 0, stream>>>(csum);
    scan_pass3<<<dim3(64, B_SZ), 256, 0, stream>>>(ms_inp, csum, msh);
    // 5) SSM-in GEMM + GELU -> yh (fp16 swizzled)
    gemm_go_mfma<<<dim3(256, 4), 256, 0, stream>>>(xh, msh, Wgoh, bgo, yh);
    // 6) output GEMM + GLU -> out (f32)
    gemm_out_mfma<<<dim3(256, 8), 256, 0, stream>>>(yh, Wouth, bout, out);
}